// Round 1
// 263.673 us; speedup vs baseline: 1.0881x; 1.0881x over previous
//
#include <hip/hip_runtime.h>
#include <hip/hip_bf16.h>

typedef __attribute__((ext_vector_type(8))) short v8s;   // 8 x bf16 (4 VGPRs)
typedef __attribute__((ext_vector_type(4))) float v4f;   // float4 / MFMA acc

constexpr int H  = 256;   // hidden channels
constexpr int K2 = 512;   // 2H
constexpr int XS = 72;    // padded LDS stride (bf16 elems) -- fallback kernel
constexpr int WS = 72;

__device__ inline unsigned short f2bf(float f) {         // fp32 -> bf16 bits, RNE
    unsigned int u = __builtin_bit_cast(unsigned int, f);
    u += 0x7FFFu + ((u >> 16) & 1u);
    return (unsigned short)(u >> 16);
}
__device__ inline float bf2f(unsigned short s) {
    return __builtin_bit_cast(float, (unsigned int)s << 16);
}

// raw barrier: LDS-drain only; global loads stay in flight across it
#define BAR_LGKM() do {                                          \
    asm volatile("s_waitcnt lgkmcnt(0)" ::: "memory");           \
    __builtin_amdgcn_sched_barrier(0);                           \
    __builtin_amdgcn_s_barrier();                                \
    __builtin_amdgcn_sched_barrier(0);                           \
} while (0)

// ---- pre-kernel: W1 fp32 [512][256] (k-major) -> W1T bf16 [256][512] (n-major) ----
__global__ void w1_transpose_kernel(const float* __restrict__ w1,
                                    unsigned short* __restrict__ w1t) {
    __shared__ float tile[32][33];
    const int bk = blockIdx.x;
    const int bn = blockIdx.y;
    const int tx = threadIdx.x & 31;
    const int ty8 = threadIdx.x >> 5;
#pragma unroll
    for (int i = 0; i < 4; ++i) {
        int ty = i * 8 + ty8;
        tile[ty][tx] = w1[(size_t)(bk * 32 + ty) * H + bn * 32 + tx];
    }
    __syncthreads();
#pragma unroll
    for (int i = 0; i < 4; ++i) {
        int ty = i * 8 + ty8;
        w1t[(size_t)(bn * 32 + ty) * K2 + bk * 32 + tx] = f2bf(tile[tx][ty]);
    }
}

// ---- chunk-referenced flags (64-row granularity), computed from actual edges ----
__global__ void flag_zero_kernel(unsigned char* __restrict__ f, const int n) {
    int i = threadIdx.x + blockIdx.x * blockDim.x;
    int stride = blockDim.x * gridDim.x;
    for (; i < n; i += stride) f[i] = 0;
}

__global__ void flag_fill_kernel(const int* __restrict__ eli,
                                 unsigned char* __restrict__ fu,
                                 unsigned char* __restrict__ fm,
                                 const int E, const int nu, const int nm) {
    const long stride = (long)blockDim.x * gridDim.x;
    for (long e = threadIdx.x + (long)blockIdx.x * blockDim.x; e < E; e += stride) {
        int u = eli[e];
        int m = eli[(long)E + e];
        u = u < 0 ? 0 : (u >= nu ? nu - 1 : u);   // same clamp as edge_score_kernel
        m = m < 0 ? 0 : (m >= nm ? nm - 1 : m);
        fu[u >> 6] = 1;
        fm[m >> 6] = 1;
    }
}

// ---- persistent fused dense GEMM over BOTH tables ----
// grid = 256 blocks (1/CU), 512 thr = 8 waves. Even blocks: user side, odd: movie.
// B (W1T side, 256x256 bf16) lives in REGISTERS: per lane 32 x v8s = 128 VGPR,
// loaded once from L2. X chunk (64 rows) staged in one 32 KB XOR-swizzled LDS
// buffer; 2-chunk-deep register prefetch; raw s_barrier (lgkm-drain only) so the
// X prefetch loads stay in flight across barriers. Inactive chunks are skipped
// via the edge-derived flags (compacted list per block).
__global__ __launch_bounds__(512, 2) void emb_gemm_persist_kernel(
    const float* __restrict__ user_emb,
    const float* __restrict__ movie_emb,
    const unsigned short* __restrict__ w1t, // [256][512] bf16
    const float* __restrict__ b1,           // [256]
    unsigned short* __restrict__ P,         // [n_users][256] bf16
    unsigned short* __restrict__ Q,         // [n_movies][256] bf16
    const int n_users, const int n_movies,
    const unsigned char* __restrict__ fu,
    const unsigned char* __restrict__ fm)
{
    __shared__ __align__(16) unsigned short Xs[64 * 256];  // 32 KiB
    __shared__ int list[64];
    __shared__ int nact_s;

    const int bid   = blockIdx.x;
    const int nside = (int)(gridDim.x >> 1);          // blocks per side (128)
    const int isMovie = bid & 1;
    const int base  = bid >> 1;

    const float* emb = isMovie ? movie_emb : user_emb;
    unsigned short* outp = isMovie ? Q : P;
    const int M    = isMovie ? n_movies : n_users;
    const int kofs = isMovie ? 256 : 0;
    const int nch  = (M + 63) >> 6;
    const unsigned char* flags = isMovie ? fm : fu;

    const int t    = threadIdx.x;
    const int wave = t >> 6;
    const int lane = t & 63;
    const int wm   = wave >> 2;   // 0..1 : 32-row half
    const int wn   = wave & 3;    // 0..3 : 64-col slice
    const int quad = lane >> 4;
    const int l16  = lane & 15;

    // compacted active-chunk list (ballot over wave 0; covers nch <= 64*nside)
    if (wave == 0) {
        int c = base + lane * nside;
        bool a = (c < nch) && (flags[c] != 0);
        unsigned long long mk = __ballot(a);
        if (a) list[__popcll(mk & ((1ull << lane) - 1ull))] = c;
        if (lane == 0) nact_s = (int)__popcll(mk);
    }
    __syncthreads();
    const int nact = nact_s;
    if (nact == 0) return;

    // ---- B fragments into registers (one-time, w1t is L2-hot) ----
    v8s B[4][4][2];   // [nt][kt][ks] : 128 VGPRs
    {
        const unsigned short* wb = w1t + (size_t)(wn * 64 + l16) * K2 + kofs + quad * 8;
#pragma unroll
        for (int nt = 0; nt < 4; ++nt)
#pragma unroll
            for (int kt = 0; kt < 4; ++kt)
#pragma unroll
                for (int ks = 0; ks < 2; ++ks)
                    B[nt][kt][ks] = *(const v8s*)(wb + (size_t)nt * 16 * K2 + kt * 64 + ks * 32);
    }
    float bv[4];
#pragma unroll
    for (int nt = 0; nt < 4; ++nt)
        bv[nt] = isMovie ? 0.f : b1[wn * 64 + nt * 16 + l16];

    char* const xsb = (char*)Xs;
    v4f xq[8];   // one X chunk in regs: wave w owns rows w*8..w*8+7, lane owns 4 cols

    auto LOADX = [&](int c) {
#pragma unroll
        for (int i = 0; i < 8; ++i) {
            long r = (long)c * 64 + wave * 8 + i;
            if (r >= M) r = M - 1;
            xq[i] = *(const v4f*)(emb + (size_t)r * H + lane * 4);   // 1 KiB/row, wave-contiguous
        }
    };
    auto WRITEX = [&]() {   // cvt fp32->bf16, XOR-swizzled ds_write_b64
#pragma unroll
        for (int i = 0; i < 8; ++i) {
            const int r = wave * 8 + i;                 // r & 7 == i
            unsigned int lo = (unsigned)f2bf(xq[i][0]) | ((unsigned)f2bf(xq[i][1]) << 16);
            unsigned int hi = (unsigned)f2bf(xq[i][2]) | ((unsigned)f2bf(xq[i][3]) << 16);
            *(unsigned long long*)(xsb + r * 512 + ((lane * 8) ^ (i << 4))) =
                ((unsigned long long)hi << 32) | lo;
        }
    };

    // prologue: stage chunk 0, prefetch chunk 1
    LOADX(list[0]);
    WRITEX();
    if (nact > 1) LOADX(list[1]);
    __syncthreads();

    for (int j = 0; j < nact; ++j) {
        const long m0 = (long)list[j] * 64;

        v4f acc[2][4];
#pragma unroll
        for (int mt = 0; mt < 2; ++mt)
#pragma unroll
            for (int nt = 0; nt < 4; ++nt)
                acc[mt][nt] = (v4f){0.f, 0.f, 0.f, 0.f};

        // 64 MFMA per wave per chunk, pure ds_read + reg-B
#pragma unroll
        for (int kt = 0; kt < 4; ++kt)
#pragma unroll
            for (int ks = 0; ks < 2; ++ks) {
                v8s af[2];
#pragma unroll
                for (int mt = 0; mt < 2; ++mt) {
                    const int row = wm * 32 + mt * 16 + l16;
                    af[mt] = *(const v8s*)(xsb + row * 512 +
                        ((kt * 128 + ks * 64 + quad * 16) ^ ((l16 & 7) << 4)));
                }
#pragma unroll
                for (int mt = 0; mt < 2; ++mt)
#pragma unroll
                    for (int nt = 0; nt < 4; ++nt)
                        acc[mt][nt] = __builtin_amdgcn_mfma_f32_16x16x32_bf16(
                            af[mt], B[nt][kt][ks], acc[mt][nt], 0, 0, 0);
            }

        // epilogue: (+b1 for user side), bf16 store. D: col=l16, row=quad*4+j4
#pragma unroll
        for (int mt = 0; mt < 2; ++mt)
#pragma unroll
            for (int j4 = 0; j4 < 4; ++j4) {
                const long m = m0 + wm * 32 + mt * 16 + quad * 4 + j4;
                if (m < M) {
#pragma unroll
                    for (int nt = 0; nt < 4; ++nt)
                        outp[(size_t)m * H + wn * 64 + nt * 16 + l16] =
                            f2bf(acc[mt][nt][j4] + bv[nt]);
                }
            }

        if (j + 1 < nact) {
            BAR_LGKM();                      // all waves done reading Xs(list[j])
            WRITEX();                        // stage chunk list[j+1] (vmcnt wait via reg dep)
            if (j + 2 < nact) LOADX(list[j + 2]);   // issue next prefetch...
            BAR_LGKM();                      // ...which stays in flight across this barrier
        }
    }
}

// ---- edge pass: out[e] = relu(P[u] + Q[m]) . w2 + b2 ----
// block 256 thr = 8 half-waves; each half-wave does 8 edges; row loads double-buffered
__global__ __launch_bounds__(256, 8) void edge_score_kernel(
    const unsigned short* __restrict__ P,
    const unsigned short* __restrict__ Q,
    const int* __restrict__ eli,
    const float* __restrict__ w2,
    const float* __restrict__ b2,
    float* __restrict__ out,
    const int E, const int n_users, const int n_movies)
{
    const int t   = threadIdx.x;
    const int hw  = t >> 5;        // 0..7
    const int l32 = t & 31;

    float w2v[8];
    {
        v4f a = *(const v4f*)(w2 + l32 * 8);
        v4f b = *(const v4f*)(w2 + l32 * 8 + 4);
#pragma unroll
        for (int i = 0; i < 4; ++i) { w2v[i] = a[i]; w2v[4 + i] = b[i]; }
    }
    const float b2v = b2[0];
    const long base = (long)blockIdx.x * 64;

    // preload all 16 indices (independent loads issue together)
    int us[8], ms[8];
#pragma unroll
    for (int i = 0; i < 8; ++i) {
        long e = base + i * 8 + hw;
        long ec = (e < E) ? e : 0;
        int u = eli[ec];
        int m = eli[(long)E + ec];
        us[i] = u < 0 ? 0 : (u >= n_users  ? n_users  - 1 : u);
        ms[i] = m < 0 ? 0 : (m >= n_movies ? n_movies - 1 : m);
    }

    v8s pv = *(const v8s*)(P + (size_t)us[0] * H + l32 * 8);
    v8s qv = *(const v8s*)(Q + (size_t)ms[0] * H + l32 * 8);

#pragma unroll
    for (int i = 0; i < 8; ++i) {
        v8s pn, qn;
        if (i < 7) {                                   // next rows issue before compute
            pn = *(const v8s*)(P + (size_t)us[i + 1] * H + l32 * 8);
            qn = *(const v8s*)(Q + (size_t)ms[i + 1] * H + l32 * 8);
        }
        float s = 0.f;
#pragma unroll
        for (int j = 0; j < 8; ++j) {
            float h = bf2f((unsigned short)pv[j]) + bf2f((unsigned short)qv[j]);
            h = h > 0.f ? h : 0.f;
            s += h * w2v[j];
        }
        s += __shfl_xor(s, 1, 64);
        s += __shfl_xor(s, 2, 64);
        s += __shfl_xor(s, 4, 64);
        s += __shfl_xor(s, 8, 64);
        s += __shfl_xor(s, 16, 64);
        long e = base + i * 8 + hw;
        if (l32 == 0 && e < E) out[e] = s + b2v;
        pv = pn; qv = qn;
    }
}

// ================= round-6 fallback (verified) — used if ws_size too small ==========
constexpr int BMF = 64;
__global__ __launch_bounds__(512, 4) void edge_decoder_kernel(
    const float* __restrict__ user_emb, const float* __restrict__ movie_emb,
    const int* __restrict__ eli, const unsigned short* __restrict__ w1t,
    const float* __restrict__ b1, const float* __restrict__ w2,
    const float* __restrict__ b2, float* __restrict__ out,
    const int E, const int n_users, const int n_movies)
{
    __shared__ unsigned short Xs[BMF * XS];
    __shared__ unsigned short Wts[H * WS];
    __shared__ float red[4][BMF];
    const int t = threadIdx.x, wave = t >> 6, lane = t & 63;
    const int wm = wave >> 2, wn = wave & 3, quad = lane >> 4, l16 = lane & 15;
    const long e0 = (long)blockIdx.x * BMF;
    const int xr = t >> 3, xc = t & 7;
    long eg = e0 + xr; if (eg >= E) eg = 0;
    int iu = eli[eg], im = eli[(long)E + eg];
    iu = iu < 0 ? 0 : (iu >= n_users ? n_users - 1 : iu);
    im = im < 0 ? 0 : (im >= n_movies ? n_movies - 1 : im);
    const float* urow = user_emb + (size_t)iu * H;
    const float* mrow = movie_emb + (size_t)im * H;
    const int wr = t >> 3, wc8 = t & 7;
    const unsigned short* wbase = w1t + (size_t)wr * K2 + wc8 * 8;
    v4f acc[2][4];
#pragma unroll
    for (int mt = 0; mt < 2; ++mt)
#pragma unroll
        for (int nt = 0; nt < 4; ++nt) acc[mt][nt] = (v4f){0.f,0.f,0.f,0.f};
    v4f xq0 = *(const v4f*)(urow + xc * 8);
    v4f xq1 = *(const v4f*)(urow + xc * 8 + 4);
    v8s wq[4];
#pragma unroll
    for (int j = 0; j < 4; ++j) wq[j] = *(const v8s*)(wbase + (size_t)j * 64 * K2);
    for (int kt = 0; kt < 8; ++kt) {
        __syncthreads();
        { v8s xv;
#pragma unroll
          for (int i = 0; i < 4; ++i) xv[i] = (short)f2bf(xq0[i]);
#pragma unroll
          for (int i = 0; i < 4; ++i) xv[4+i] = (short)f2bf(xq1[i]);
          *(v8s*)(Xs + xr * XS + xc * 8) = xv; }
#pragma unroll
        for (int j = 0; j < 4; ++j) *(v8s*)(Wts + (j * 64 + wr) * WS + wc8 * 8) = wq[j];
        if (kt < 7) {
            const int kn = kt + 1, koff = (kn * 64) & 255;
            const float* src = ((kn < 4) ? urow : mrow) + koff + xc * 8;
            xq0 = *(const v4f*)(src); xq1 = *(const v4f*)(src + 4);
#pragma unroll
            for (int j = 0; j < 4; ++j) wq[j] = *(const v8s*)(wbase + (size_t)j * 64 * K2 + kn * 64);
        }
        __syncthreads();
#pragma unroll
        for (int ks = 0; ks < 2; ++ks) {
            v8s af[2], bf[4];
#pragma unroll
            for (int mt = 0; mt < 2; ++mt)
                af[mt] = *(const v8s*)(Xs + (wm * 32 + mt * 16 + l16) * XS + ks * 32 + quad * 8);
#pragma unroll
            for (int nt = 0; nt < 4; ++nt)
                bf[nt] = *(const v8s*)(Wts + (wn * 64 + nt * 16 + l16) * WS + ks * 32 + quad * 8);
#pragma unroll
            for (int mt = 0; mt < 2; ++mt)
#pragma unroll
                for (int nt = 0; nt < 4; ++nt)
                    acc[mt][nt] = __builtin_amdgcn_mfma_f32_16x16x32_bf16(af[mt], bf[nt], acc[mt][nt], 0, 0, 0);
        }
    }
    float b1v[4], w2v[4];
#pragma unroll
    for (int nt = 0; nt < 4; ++nt) {
        int n = wn * 64 + nt * 16 + l16;
        b1v[nt] = b1[n]; w2v[nt] = w2[n];
    }
    const float b2v = b2[0];
#pragma unroll
    for (int mt = 0; mt < 2; ++mt) {
        float s[4] = {0.f,0.f,0.f,0.f};
#pragma unroll
        for (int nt = 0; nt < 4; ++nt)
#pragma unroll
            for (int j = 0; j < 4; ++j) {
                float h = acc[mt][nt][j] + b1v[nt];
                h = h > 0.f ? h : 0.f;
                s[j] += h * w2v[nt];
            }
#pragma unroll
        for (int j = 0; j < 4; ++j) {
            float v = s[j];
            v += __shfl_xor(v, 1, 64); v += __shfl_xor(v, 2, 64);
            v += __shfl_xor(v, 4, 64); v += __shfl_xor(v, 8, 64);
            if (l16 == 0) red[wn][wm * 32 + mt * 16 + quad * 4 + j] = v;
        }
    }
    __syncthreads();
    if (t < BMF) {
        long e = e0 + t;
        if (e < E) out[e] = red[0][t] + red[1][t] + red[2][t] + red[3][t] + b2v;
    }
}

extern "C" void kernel_launch(void* const* d_in, const int* in_sizes, int n_in,
                              void* d_out, int out_size, void* d_ws, size_t ws_size,
                              hipStream_t stream) {
    const float* user_emb  = (const float*)d_in[0];
    const float* movie_emb = (const float*)d_in[1];
    const int*   eli       = (const int*)d_in[2];
    const float* w1        = (const float*)d_in[3];
    const float* b1        = (const float*)d_in[4];
    const float* w2        = (const float*)d_in[5];
    const float* b2        = (const float*)d_in[6];
    float*       out       = (float*)d_out;

    const int E        = out_size;
    const int n_users  = in_sizes[0] / H;
    const int n_movies = in_sizes[1] / H;

    unsigned short* w1t = (unsigned short*)d_ws;                 // 256 KiB
    const size_t w1t_bytes = (size_t)K2 * H * 2;
    const size_t p_bytes   = (size_t)n_users  * H * 2;
    const size_t q_bytes   = (size_t)n_movies * H * 2;

    const int nbu = (n_users  + 63) / 64;
    const int nbm = (n_movies + 63) / 64;
    const size_t flag_bytes = (size_t)nbu + (size_t)nbm;

    w1_transpose_kernel<<<dim3(16, 8), 256, 0, stream>>>(w1, w1t);

    // persistent path needs: w1t + P + Q + flags, and chunk counts within the
    // per-block ballot capacity (64 slots x 128 blocks/side)
    if (ws_size >= w1t_bytes + p_bytes + q_bytes + flag_bytes &&
        nbu <= 64 * 128 && nbm <= 64 * 128) {
        unsigned short* P = (unsigned short*)((char*)d_ws + w1t_bytes);
        unsigned short* Q = (unsigned short*)((char*)d_ws + w1t_bytes + p_bytes);
        unsigned char*  fu = (unsigned char*)((char*)d_ws + w1t_bytes + p_bytes + q_bytes);
        unsigned char*  fm = fu + nbu;

        flag_zero_kernel<<<4, 256, 0, stream>>>(fu, nbu + nbm);
        if (E > 0)
            flag_fill_kernel<<<512, 256, 0, stream>>>(eli, fu, fm, E, n_users, n_movies);
        emb_gemm_persist_kernel<<<256, 512, 0, stream>>>(
            user_emb, movie_emb, w1t, b1, P, Q, n_users, n_movies, fu, fm);
        if (E > 0)
            edge_score_kernel<<<(E + 63) / 64, 256, 0, stream>>>(
                P, Q, eli, w2, b2, out, E, n_users, n_movies);
    } else {
        if (E > 0)
            edge_decoder_kernel<<<(E + BMF - 1) / BMF, 512, 0, stream>>>(
                user_emb, movie_emb, eli, w1t, b1, w2, b2, out, E, n_users, n_movies);
    }
}

// Round 2
// 263.186 us; speedup vs baseline: 1.0901x; 1.0019x over previous
//
#include <hip/hip_runtime.h>
#include <hip/hip_bf16.h>

typedef __attribute__((ext_vector_type(8))) short v8s;   // 8 x bf16 (4 VGPRs)
typedef __attribute__((ext_vector_type(4))) float v4f;   // float4 / MFMA acc

constexpr int H  = 256;   // hidden channels
constexpr int K2 = 512;   // 2H
constexpr int XS = 72;    // padded LDS stride (bf16 elems) -- fallback kernel
constexpr int WS = 72;

__device__ inline unsigned short f2bf(float f) {         // fp32 -> bf16 bits, RNE
    unsigned int u = __builtin_bit_cast(unsigned int, f);
    u += 0x7FFFu + ((u >> 16) & 1u);
    return (unsigned short)(u >> 16);
}
__device__ inline float bf2f(unsigned short s) {
    return __builtin_bit_cast(float, (unsigned int)s << 16);
}

// raw barrier: LDS-drain only; global loads stay in flight across it
#define BAR_LGKM() do {                                          \
    asm volatile("s_waitcnt lgkmcnt(0)" ::: "memory");           \
    __builtin_amdgcn_sched_barrier(0);                           \
    __builtin_amdgcn_s_barrier();                                \
    __builtin_amdgcn_sched_barrier(0);                           \
} while (0)

// ---- pre-kernel: W1 fp32 [512][256] (k-major) -> W1T bf16 [256][512] (n-major) ----
// also zeroes the chunk-flag arrays (block 0) to save a launch
__global__ void w1_transpose_kernel(const float* __restrict__ w1,
                                    unsigned short* __restrict__ w1t,
                                    unsigned char* __restrict__ flags,
                                    const int nflags) {
    __shared__ float tile[32][33];
    const int bk = blockIdx.x;
    const int bn = blockIdx.y;
    const int tx = threadIdx.x & 31;
    const int ty8 = threadIdx.x >> 5;
    if (flags && bk == 0 && bn == 0) {
        for (int i = threadIdx.x; i < nflags; i += 256) flags[i] = 0;
    }
#pragma unroll
    for (int i = 0; i < 4; ++i) {
        int ty = i * 8 + ty8;
        tile[ty][tx] = w1[(size_t)(bk * 32 + ty) * H + bn * 32 + tx];
    }
    __syncthreads();
#pragma unroll
    for (int i = 0; i < 4; ++i) {
        int ty = i * 8 + ty8;
        w1t[(size_t)(bn * 32 + ty) * K2 + bk * 32 + tx] = f2bf(tile[tx][ty]);
    }
}

__global__ void flag_fill_kernel(const int* __restrict__ eli,
                                 unsigned char* __restrict__ fu,
                                 unsigned char* __restrict__ fm,
                                 const int E, const int nu, const int nm) {
    const long stride = (long)blockDim.x * gridDim.x;
    for (long e = threadIdx.x + (long)blockIdx.x * blockDim.x; e < E; e += stride) {
        int u = eli[e];
        int m = eli[(long)E + e];
        u = u < 0 ? 0 : (u >= nu ? nu - 1 : u);   // same clamp as edge_score_kernel
        m = m < 0 ? 0 : (m >= nm ? nm - 1 : m);
        fu[u >> 6] = 1;
        fm[m >> 6] = 1;
    }
}

// ---- persistent fused dense GEMM over BOTH tables ----
// grid = 256 blocks (1/CU), 512 thr = 8 waves. Even blocks: user side, odd: movie.
// B (W1T side, 256x256 bf16) lives in REGISTERS: per lane 32 x v8s = 128 VGPR,
// loaded once from L2. X chunk (64 rows) staged in one 32 KB XOR-swizzled LDS
// buffer; 2-chunk-deep register prefetch; raw s_barrier (lgkm-drain only) so the
// X prefetch loads stay in flight across barriers. Inactive chunks are skipped
// via the edge-derived flags (compacted list per block).
__global__ __launch_bounds__(512, 2) void emb_gemm_persist_kernel(
    const float* __restrict__ user_emb,
    const float* __restrict__ movie_emb,
    const unsigned short* __restrict__ w1t, // [256][512] bf16
    const float* __restrict__ b1,           // [256]
    unsigned short* __restrict__ P,         // [n_users][256] bf16
    unsigned short* __restrict__ Q,         // [n_movies][256] bf16
    const int n_users, const int n_movies,
    const unsigned char* __restrict__ fu,
    const unsigned char* __restrict__ fm)
{
    __shared__ __align__(16) unsigned short Xs[64 * 256];  // 32 KiB
    __shared__ int list[64];
    __shared__ int nact_s;

    const int bid   = blockIdx.x;
    const int nside = (int)(gridDim.x >> 1);          // blocks per side (128)
    const int isMovie = bid & 1;
    const int base  = bid >> 1;

    const float* emb = isMovie ? movie_emb : user_emb;
    unsigned short* outp = isMovie ? Q : P;
    const int M    = isMovie ? n_movies : n_users;
    const int kofs = isMovie ? 256 : 0;
    const int nch  = (M + 63) >> 6;
    const unsigned char* flags = isMovie ? fm : fu;

    const int t    = threadIdx.x;
    const int wave = t >> 6;
    const int lane = t & 63;
    const int wm   = wave >> 2;   // 0..1 : 32-row half
    const int wn   = wave & 3;    // 0..3 : 64-col slice
    const int quad = lane >> 4;
    const int l16  = lane & 15;

    // compacted active-chunk list (ballot over wave 0; covers nch <= 64*nside)
    if (wave == 0) {
        int c = base + lane * nside;
        bool a = (c < nch) && (flags[c] != 0);
        unsigned long long mk = __ballot(a);
        if (a) list[__popcll(mk & ((1ull << lane) - 1ull))] = c;
        if (lane == 0) nact_s = (int)__popcll(mk);
    }
    __syncthreads();
    const int nact = nact_s;
    if (nact == 0) return;

    // ---- B fragments into registers (one-time, w1t is L2-hot) ----
    v8s B[4][4][2];   // [nt][kt][ks] : 128 VGPRs
    {
        const unsigned short* wb = w1t + (size_t)(wn * 64 + l16) * K2 + kofs + quad * 8;
#pragma unroll
        for (int nt = 0; nt < 4; ++nt)
#pragma unroll
            for (int kt = 0; kt < 4; ++kt)
#pragma unroll
                for (int ks = 0; ks < 2; ++ks)
                    B[nt][kt][ks] = *(const v8s*)(wb + (size_t)nt * 16 * K2 + kt * 64 + ks * 32);
    }
    float bv[4];
#pragma unroll
    for (int nt = 0; nt < 4; ++nt)
        bv[nt] = isMovie ? 0.f : b1[wn * 64 + nt * 16 + l16];

    char* const xsb = (char*)Xs;
    v4f xq[8];   // one X chunk in regs: wave w owns rows w*8..w*8+7, lane owns 4 cols

    auto LOADX = [&](int c) {
#pragma unroll
        for (int i = 0; i < 8; ++i) {
            long r = (long)c * 64 + wave * 8 + i;
            if (r >= M) r = M - 1;
            xq[i] = *(const v4f*)(emb + (size_t)r * H + lane * 4);   // 1 KiB/row, wave-contiguous
        }
    };
    auto WRITEX = [&]() {   // cvt fp32->bf16, XOR-swizzled ds_write_b64
#pragma unroll
        for (int i = 0; i < 8; ++i) {
            const int r = wave * 8 + i;                 // r & 7 == i
            unsigned int lo = (unsigned)f2bf(xq[i][0]) | ((unsigned)f2bf(xq[i][1]) << 16);
            unsigned int hi = (unsigned)f2bf(xq[i][2]) | ((unsigned)f2bf(xq[i][3]) << 16);
            *(unsigned long long*)(xsb + r * 512 + ((lane * 8) ^ (i << 4))) =
                ((unsigned long long)hi << 32) | lo;
        }
    };

    // prologue: stage chunk 0, prefetch chunk 1
    LOADX(list[0]);
    WRITEX();
    if (nact > 1) LOADX(list[1]);
    __syncthreads();

    for (int j = 0; j < nact; ++j) {
        const long m0 = (long)list[j] * 64;

        v4f acc[2][4];
#pragma unroll
        for (int mt = 0; mt < 2; ++mt)
#pragma unroll
            for (int nt = 0; nt < 4; ++nt)
                acc[mt][nt] = (v4f){0.f, 0.f, 0.f, 0.f};

        // 64 MFMA per wave per chunk, pure ds_read + reg-B
#pragma unroll
        for (int kt = 0; kt < 4; ++kt)
#pragma unroll
            for (int ks = 0; ks < 2; ++ks) {
                v8s af[2];
#pragma unroll
                for (int mt = 0; mt < 2; ++mt) {
                    const int row = wm * 32 + mt * 16 + l16;
                    af[mt] = *(const v8s*)(xsb + row * 512 +
                        ((kt * 128 + ks * 64 + quad * 16) ^ ((l16 & 7) << 4)));
                }
#pragma unroll
                for (int mt = 0; mt < 2; ++mt)
#pragma unroll
                    for (int nt = 0; nt < 4; ++nt)
                        acc[mt][nt] = __builtin_amdgcn_mfma_f32_16x16x32_bf16(
                            af[mt], B[nt][kt][ks], acc[mt][nt], 0, 0, 0);
            }

        // epilogue: (+b1 for user side), bf16 store. D: col=l16, row=quad*4+j4
#pragma unroll
        for (int mt = 0; mt < 2; ++mt)
#pragma unroll
            for (int j4 = 0; j4 < 4; ++j4) {
                const long m = m0 + wm * 32 + mt * 16 + quad * 4 + j4;
                if (m < M) {
#pragma unroll
                    for (int nt = 0; nt < 4; ++nt)
                        outp[(size_t)m * H + wn * 64 + nt * 16 + l16] =
                            f2bf(acc[mt][nt][j4] + bv[nt]);
                }
            }

        if (j + 1 < nact) {
            BAR_LGKM();                      // all waves done reading Xs(list[j])
            WRITEX();                        // stage chunk list[j+1] (vmcnt wait via reg dep)
            if (j + 2 < nact) LOADX(list[j + 2]);   // issue next prefetch...
            BAR_LGKM();                      // ...which stays in flight across this barrier
        }
    }
}

// ---- edge pass: out[e] = relu(P[u] + Q[m]) . w2 + b2 ----
// block 256 thr = 8 half-waves; each half-wave does 8 edges.
// ALL 16 row loads issued up front (full-depth pipeline): in-flight bytes/wave
// 2 KB -> 8 KB; launch_bounds relaxed to 4 waves/EU for the VGPR budget.
__global__ __launch_bounds__(256, 4) void edge_score_kernel(
    const unsigned short* __restrict__ P,
    const unsigned short* __restrict__ Q,
    const int* __restrict__ eli,
    const float* __restrict__ w2,
    const float* __restrict__ b2,
    float* __restrict__ out,
    const int E, const int n_users, const int n_movies)
{
    const int t   = threadIdx.x;
    const int hw  = t >> 5;        // 0..7
    const int l32 = t & 31;

    float w2v[8];
    {
        v4f a = *(const v4f*)(w2 + l32 * 8);
        v4f b = *(const v4f*)(w2 + l32 * 8 + 4);
#pragma unroll
        for (int i = 0; i < 4; ++i) { w2v[i] = a[i]; w2v[4 + i] = b[i]; }
    }
    const float b2v = b2[0];
    const long base = (long)blockIdx.x * 64;

    // preload all 16 indices (independent loads issue together)
    int us[8], ms[8];
#pragma unroll
    for (int i = 0; i < 8; ++i) {
        long e = base + i * 8 + hw;
        long ec = (e < E) ? e : 0;
        int u = eli[ec];
        int m = eli[(long)E + ec];
        us[i] = u < 0 ? 0 : (u >= n_users  ? n_users  - 1 : u);
        ms[i] = m < 0 ? 0 : (m >= n_movies ? n_movies - 1 : m);
    }

    // issue ALL row loads before any compute (16 outstanding per thread-pair)
    v8s pv[8], qv[8];
#pragma unroll
    for (int i = 0; i < 8; ++i) {
        pv[i] = *(const v8s*)(P + (size_t)us[i] * H + l32 * 8);
        qv[i] = *(const v8s*)(Q + (size_t)ms[i] * H + l32 * 8);
    }

#pragma unroll
    for (int i = 0; i < 8; ++i) {
        float s = 0.f;
#pragma unroll
        for (int j = 0; j < 8; ++j) {
            float h = bf2f((unsigned short)pv[i][j]) + bf2f((unsigned short)qv[i][j]);
            h = h > 0.f ? h : 0.f;
            s += h * w2v[j];
        }
        s += __shfl_xor(s, 1, 64);
        s += __shfl_xor(s, 2, 64);
        s += __shfl_xor(s, 4, 64);
        s += __shfl_xor(s, 8, 64);
        s += __shfl_xor(s, 16, 64);
        long e = base + i * 8 + hw;
        if (l32 == 0 && e < E) out[e] = s + b2v;
    }
}

// ================= round-6 fallback (verified) — used if ws_size too small ==========
constexpr int BMF = 64;
__global__ __launch_bounds__(512, 4) void edge_decoder_kernel(
    const float* __restrict__ user_emb, const float* __restrict__ movie_emb,
    const int* __restrict__ eli, const unsigned short* __restrict__ w1t,
    const float* __restrict__ b1, const float* __restrict__ w2,
    const float* __restrict__ b2, float* __restrict__ out,
    const int E, const int n_users, const int n_movies)
{
    __shared__ unsigned short Xs[BMF * XS];
    __shared__ unsigned short Wts[H * WS];
    __shared__ float red[4][BMF];
    const int t = threadIdx.x, wave = t >> 6, lane = t & 63;
    const int wm = wave >> 2, wn = wave & 3, quad = lane >> 4, l16 = lane & 15;
    const long e0 = (long)blockIdx.x * BMF;
    const int xr = t >> 3, xc = t & 7;
    long eg = e0 + xr; if (eg >= E) eg = 0;
    int iu = eli[eg], im = eli[(long)E + eg];
    iu = iu < 0 ? 0 : (iu >= n_users ? n_users - 1 : iu);
    im = im < 0 ? 0 : (im >= n_movies ? n_movies - 1 : im);
    const float* urow = user_emb + (size_t)iu * H;
    const float* mrow = movie_emb + (size_t)im * H;
    const int wr = t >> 3, wc8 = t & 7;
    const unsigned short* wbase = w1t + (size_t)wr * K2 + wc8 * 8;
    v4f acc[2][4];
#pragma unroll
    for (int mt = 0; mt < 2; ++mt)
#pragma unroll
        for (int nt = 0; nt < 4; ++nt) acc[mt][nt] = (v4f){0.f,0.f,0.f,0.f};
    v4f xq0 = *(const v4f*)(urow + xc * 8);
    v4f xq1 = *(const v4f*)(urow + xc * 8 + 4);
    v8s wq[4];
#pragma unroll
    for (int j = 0; j < 4; ++j) wq[j] = *(const v8s*)(wbase + (size_t)j * 64 * K2);
    for (int kt = 0; kt < 8; ++kt) {
        __syncthreads();
        { v8s xv;
#pragma unroll
          for (int i = 0; i < 4; ++i) xv[i] = (short)f2bf(xq0[i]);
#pragma unroll
          for (int i = 0; i < 4; ++i) xv[4+i] = (short)f2bf(xq1[i]);
          *(v8s*)(Xs + xr * XS + xc * 8) = xv; }
#pragma unroll
        for (int j = 0; j < 4; ++j) *(v8s*)(Wts + (j * 64 + wr) * WS + wc8 * 8) = wq[j];
        if (kt < 7) {
            const int kn = kt + 1, koff = (kn * 64) & 255;
            const float* src = ((kn < 4) ? urow : mrow) + koff + xc * 8;
            xq0 = *(const v4f*)(src); xq1 = *(const v4f*)(src + 4);
#pragma unroll
            for (int j = 0; j < 4; ++j) wq[j] = *(const v8s*)(wbase + (size_t)j * 64 * K2 + kn * 64);
        }
        __syncthreads();
#pragma unroll
        for (int ks = 0; ks < 2; ++ks) {
            v8s af[2], bf[4];
#pragma unroll
            for (int mt = 0; mt < 2; ++mt)
                af[mt] = *(const v8s*)(Xs + (wm * 32 + mt * 16 + l16) * XS + ks * 32 + quad * 8);
#pragma unroll
            for (int nt = 0; nt < 4; ++nt)
                bf[nt] = *(const v8s*)(Wts + (wn * 64 + nt * 16 + l16) * WS + ks * 32 + quad * 8);
#pragma unroll
            for (int mt = 0; mt < 2; ++mt)
#pragma unroll
                for (int nt = 0; nt < 4; ++nt)
                    acc[mt][nt] = __builtin_amdgcn_mfma_f32_16x16x32_bf16(af[mt], bf[nt], acc[mt][nt], 0, 0, 0);
        }
    }
    float b1v[4], w2v[4];
#pragma unroll
    for (int nt = 0; nt < 4; ++nt) {
        int n = wn * 64 + nt * 16 + l16;
        b1v[nt] = b1[n]; w2v[nt] = w2[n];
    }
    const float b2v = b2[0];
#pragma unroll
    for (int mt = 0; mt < 2; ++mt) {
        float s[4] = {0.f,0.f,0.f,0.f};
#pragma unroll
        for (int nt = 0; nt < 4; ++nt)
#pragma unroll
            for (int j = 0; j < 4; ++j) {
                float h = acc[mt][nt][j] + b1v[nt];
                h = h > 0.f ? h : 0.f;
                s[j] += h * w2v[nt];
            }
#pragma unroll
        for (int j = 0; j < 4; ++j) {
            float v = s[j];
            v += __shfl_xor(v, 1, 64); v += __shfl_xor(v, 2, 64);
            v += __shfl_xor(v, 4, 64); v += __shfl_xor(v, 8, 64);
            if (l16 == 0) red[wn][wm * 32 + mt * 16 + quad * 4 + j] = v;
        }
    }
    __syncthreads();
    if (t < BMF) {
        long e = e0 + t;
        if (e < E) out[e] = red[0][t] + red[1][t] + red[2][t] + red[3][t] + b2v;
    }
}

extern "C" void kernel_launch(void* const* d_in, const int* in_sizes, int n_in,
                              void* d_out, int out_size, void* d_ws, size_t ws_size,
                              hipStream_t stream) {
    const float* user_emb  = (const float*)d_in[0];
    const float* movie_emb = (const float*)d_in[1];
    const int*   eli       = (const int*)d_in[2];
    const float* w1        = (const float*)d_in[3];
    const float* b1        = (const float*)d_in[4];
    const float* w2        = (const float*)d_in[5];
    const float* b2        = (const float*)d_in[6];
    float*       out       = (float*)d_out;

    const int E        = out_size;
    const int n_users  = in_sizes[0] / H;
    const int n_movies = in_sizes[1] / H;

    unsigned short* w1t = (unsigned short*)d_ws;                 // 256 KiB
    const size_t w1t_bytes = (size_t)K2 * H * 2;
    const size_t p_bytes   = (size_t)n_users  * H * 2;
    const size_t q_bytes   = (size_t)n_movies * H * 2;

    const int nbu = (n_users  + 63) / 64;
    const int nbm = (n_movies + 63) / 64;
    const size_t flag_bytes = (size_t)nbu + (size_t)nbm;

    // persistent path needs: w1t + P + Q + flags, and chunk counts within the
    // per-block ballot capacity (64 slots x 128 blocks/side)
    if (ws_size >= w1t_bytes + p_bytes + q_bytes + flag_bytes &&
        nbu <= 64 * 128 && nbm <= 64 * 128) {
        unsigned short* P = (unsigned short*)((char*)d_ws + w1t_bytes);
        unsigned short* Q = (unsigned short*)((char*)d_ws + w1t_bytes + p_bytes);
        unsigned char*  fu = (unsigned char*)((char*)d_ws + w1t_bytes + p_bytes + q_bytes);
        unsigned char*  fm = fu + nbu;

        w1_transpose_kernel<<<dim3(16, 8), 256, 0, stream>>>(w1, w1t, fu, nbu + nbm);
        if (E > 0)
            flag_fill_kernel<<<512, 256, 0, stream>>>(eli, fu, fm, E, n_users, n_movies);
        emb_gemm_persist_kernel<<<256, 512, 0, stream>>>(
            user_emb, movie_emb, w1t, b1, P, Q, n_users, n_movies, fu, fm);
        if (E > 0)
            edge_score_kernel<<<(E + 63) / 64, 256, 0, stream>>>(
                P, Q, eli, w2, b2, out, E, n_users, n_movies);
    } else {
        w1_transpose_kernel<<<dim3(16, 8), 256, 0, stream>>>(w1, w1t, nullptr, 0);
        if (E > 0)
            edge_decoder_kernel<<<(E + BMF - 1) / BMF, 512, 0, stream>>>(
                user_emb, movie_emb, eli, w1t, b1, w2, b2, out, E, n_users, n_movies);
    }
}